// Round 1
// baseline (29314.017 us; speedup 1.0000x reference)
//
#include <hip/hip_runtime.h>

#define HW 4096            // 64*64
#define CIN 32

// ---------------- GroupNorm (groups==channels -> per-plane instance norm) ---
// one 256-thread block per (b,c) plane of 4096 floats; plane kept in regs.
__global__ __launch_bounds__(256)
void gn_kernel(const float* __restrict__ in, float* __restrict__ out,
               const float* __restrict__ gamma, const float* __restrict__ beta,
               int do_relu)
{
    const int p = blockIdx.x;          // plane = b*32 + c
    const int c = p & 31;
    const int t = threadIdx.x;
    const float4* ip = (const float4*)(in + (size_t)p * HW);
    float4* op = (float4*)(out + (size_t)p * HW);

    float4 v[4];
    float s = 0.f, ss = 0.f;
#pragma unroll
    for (int i = 0; i < 4; ++i) {
        float4 q = ip[t + i * 256];
        v[i] = q;
        s += q.x + q.y + q.z + q.w;
        ss += q.x * q.x + q.y * q.y + q.z * q.z + q.w * q.w;
    }
#pragma unroll
    for (int off = 32; off > 0; off >>= 1) {
        s  += __shfl_xor(s, off);
        ss += __shfl_xor(ss, off);
    }
    __shared__ float red[8];
    const int wid = t >> 6;
    if ((t & 63) == 0) { red[wid] = s; red[4 + wid] = ss; }
    __syncthreads();
    s  = red[0] + red[1] + red[2] + red[3];
    ss = red[4] + red[5] + red[6] + red[7];
    const float mean = s * (1.f / HW);
    const float var  = ss * (1.f / HW) - mean * mean;
    const float rstd = rsqrtf(var + 1e-5f);
    const float sc = gamma[c] * rstd;
    const float sh = beta[c] - mean * sc;
#pragma unroll
    for (int i = 0; i < 4; ++i) {
        float4 q = v[i];
        float4 r;
        r.x = q.x * sc + sh; r.y = q.y * sc + sh;
        r.z = q.z * sc + sh; r.w = q.w * sc + sh;
        if (do_relu) {
            r.x = fmaxf(r.x, 0.f); r.y = fmaxf(r.y, 0.f);
            r.z = fmaxf(r.z, 0.f); r.w = fmaxf(r.w, 0.f);
        }
        op[t + i * 256] = r;
    }
}

// ---------------- direct 3x3 conv, 32->32, pad 1, optional constant time
// channel (index 0 of weights when HAS_TIME). Block = 256 threads:
// lane tw=w (0..63), og = t>>6 picks 8 output channels; each thread does
// 4 output rows x 8 output channels. Input tile (6 rows x 32c x 64w) in LDS.
template<int HAS_TIME>
__global__ __launch_bounds__(256)
void conv3x3_kernel(const float* __restrict__ in, float* __restrict__ out,
                    const float* __restrict__ wgt, const float* __restrict__ cb,
                    float tval)
{
    const int WS = HAS_TIME ? 33 : 32;     // weight input-channel stride
    const int blk = blockIdx.x;
    const int b = blk >> 4;
    const int h0 = (blk & 15) * 4;
    const int t = threadIdx.x;
    const int tw = t & 63;
    const int og = t >> 6;                 // 0..3

    __shared__ float smem[6][CIN][64];     // rows h0-1 .. h0+4

    const float* inb = in + (size_t)b * (CIN * HW);
    for (int i = t; i < 6 * CIN * 64; i += 256) {
        const int r = i >> 11;             // / (32*64)
        const int rem = i & 2047;
        const int c = rem >> 6;
        const int wq = rem & 63;
        const int hh = h0 - 1 + r;
        float v = 0.f;
        if (hh >= 0 && hh < 64) v = inb[(size_t)c * HW + hh * 64 + wq];
        smem[r][c][wq] = v;
    }
    __syncthreads();

    float acc[4][8];                       // [row][o8]
#pragma unroll
    for (int r = 0; r < 4; ++r)
#pragma unroll
        for (int o = 0; o < 8; ++o) acc[r][o] = 0.f;

    float iv[6][3];                        // [tile row][left,mid,right]

    for (int c = 0; c < CIN; ++c) {
#pragma unroll
        for (int r = 0; r < 6; ++r) {
            iv[r][1] = smem[r][c][tw];
            iv[r][0] = (tw > 0)  ? smem[r][c][tw - 1] : 0.f;
            iv[r][2] = (tw < 63) ? smem[r][c][tw + 1] : 0.f;
        }
        const int ci = HAS_TIME ? (c + 1) : c;
#pragma unroll
        for (int o8 = 0; o8 < 8; ++o8) {
            const int o = og * 8 + o8;
            const float* wp = wgt + ((size_t)o * WS + ci) * 9;
            float wq[9];
#pragma unroll
            for (int k = 0; k < 9; ++k) wq[k] = wp[k];   // wave-uniform addr
#pragma unroll
            for (int dy = 0; dy < 3; ++dy)
#pragma unroll
                for (int dx = 0; dx < 3; ++dx) {
                    const float wv = wq[dy * 3 + dx];
#pragma unroll
                    for (int r = 0; r < 4; ++r)
                        acc[r][o8] += iv[r + dy][dx] * wv;
                }
        }
    }

    if (HAS_TIME) {
        // time channel: constant plane of tval, zero-padded like the image
#pragma unroll
        for (int r = 0; r < 6; ++r) {
            const int hh = h0 - 1 + r;
            const float hv = (hh >= 0 && hh < 64) ? tval : 0.f;
            iv[r][1] = hv;
            iv[r][0] = (tw > 0)  ? hv : 0.f;
            iv[r][2] = (tw < 63) ? hv : 0.f;
        }
#pragma unroll
        for (int o8 = 0; o8 < 8; ++o8) {
            const int o = og * 8 + o8;
            const float* wp = wgt + ((size_t)o * WS + 0) * 9;
            float wq[9];
#pragma unroll
            for (int k = 0; k < 9; ++k) wq[k] = wp[k];
#pragma unroll
            for (int dy = 0; dy < 3; ++dy)
#pragma unroll
                for (int dx = 0; dx < 3; ++dx) {
                    const float wv = wq[dy * 3 + dx];
#pragma unroll
                    for (int r = 0; r < 4; ++r)
                        acc[r][o8] += iv[r + dy][dx] * wv;
                }
        }
    }

    const size_t ob = (size_t)b * (CIN * HW);
#pragma unroll
    for (int o8 = 0; o8 < 8; ++o8) {
        const int o = og * 8 + o8;
        const float bias = cb[o];
#pragma unroll
        for (int r = 0; r < 4; ++r)
            out[ob + (size_t)o * HW + (size_t)(h0 + r) * 64 + tw] = acc[r][o8] + bias;
    }
}

// ---------------- RK4 stage update --------------------------------------
// mode 0 (after k1): acc = y + ca*k ; yt = y + cy*k
// mode 1 (after k2/k3): acc += ca*k ; yt = y + cy*k
// mode 2 (after k4): y = acc + ca*k
__global__ __launch_bounds__(256)
void rk_update_kernel(float* __restrict__ y, const float* __restrict__ k,
                      float* __restrict__ acc, float* __restrict__ yt,
                      float ca, float cy, int mode, int n4)
{
    const int stride = gridDim.x * 256;
    float4* y4 = (float4*)y;
    const float4* k4 = (const float4*)k;
    float4* a4 = (float4*)acc;
    float4* t4 = (float4*)yt;
    for (int i = blockIdx.x * 256 + threadIdx.x; i < n4; i += stride) {
        float4 kv = k4[i];
        if (mode == 2) {
            float4 av = a4[i];
            av.x += ca * kv.x; av.y += ca * kv.y;
            av.z += ca * kv.z; av.w += ca * kv.w;
            y4[i] = av;
        } else {
            float4 yv = y4[i];
            float4 av;
            if (mode == 0) {
                av.x = yv.x + ca * kv.x; av.y = yv.y + ca * kv.y;
                av.z = yv.z + ca * kv.z; av.w = yv.w + ca * kv.w;
            } else {
                av = a4[i];
                av.x += ca * kv.x; av.y += ca * kv.y;
                av.z += ca * kv.z; av.w += ca * kv.w;
            }
            a4[i] = av;
            float4 tv;
            tv.x = yv.x + cy * kv.x; tv.y = yv.y + cy * kv.y;
            tv.z = yv.z + cy * kv.z; tv.w = yv.w + cy * kv.w;
            t4[i] = tv;
        }
    }
}

extern "C" void kernel_launch(void* const* d_in, const int* in_sizes, int n_in,
                              void* d_out, int out_size, void* d_ws, size_t ws_size,
                              hipStream_t stream) {
    (void)in_sizes; (void)n_in; (void)out_size; (void)ws_size;
    const float* x      = (const float*)d_in[0];
    const float* ai_g1  = (const float*)d_in[1];
    const float* ai_b1  = (const float*)d_in[2];
    const float* ai_w   = (const float*)d_in[3];
    const float* ai_cb  = (const float*)d_in[4];
    const float* ai_g2  = (const float*)d_in[5];
    const float* ai_b2  = (const float*)d_in[6];
    const float* ai_g3  = (const float*)d_in[7];
    const float* ai_b3  = (const float*)d_in[8];
    const float* of_g1  = (const float*)d_in[9];
    const float* of_b1  = (const float*)d_in[10];
    const float* of_w1  = (const float*)d_in[11];
    const float* of_cb1 = (const float*)d_in[12];
    const float* of_g2  = (const float*)d_in[13];
    const float* of_b2  = (const float*)d_in[14];
    const float* of_w2  = (const float*)d_in[15];
    const float* of_cb2 = (const float*)d_in[16];
    const float* of_g3  = (const float*)d_in[17];
    const float* of_b3  = (const float*)d_in[18];

    float* y = (float*)d_out;                         // state, (256,32,64,64)
    const size_t N  = (size_t)256 * 32 * 64 * 64;     // 33,554,432
    const size_t NH = N / 2;                          // batch-128 half
    float* ws  = (float*)d_ws;
    float* A   = ws;                                  // temp
    float* YT  = ws + N;                              // RK stage input / temp
    float* K   = ws + 2 * N;                          // odefunc output
    float* ACC = ws + 3 * N;                          // RK accumulator
    const int n4 = (int)(N / 4);

    const float h = 0.125f;

    // ---- atten_init (batch 128) ----
    gn_kernel<<<4096, 256, 0, stream>>>(x, A, ai_g1, ai_b1, 1);
    conv3x3_kernel<0><<<2048, 256, 0, stream>>>(A, YT, ai_w, ai_cb, 0.f);
    gn_kernel<<<4096, 256, 0, stream>>>(YT, A, ai_g2, ai_b2, 1);
    gn_kernel<<<4096, 256, 0, stream>>>(A, y + NH, ai_g3, ai_b3, 0);
    hipMemcpyAsync(y, x, NH * sizeof(float), hipMemcpyDeviceToDevice, stream);

    // ---- odefunc: yin -> K (temps A, YT; yin may be YT, consumed first) ----
    auto odefunc = [&](const float* yin, float tv) {
        gn_kernel<<<8192, 256, 0, stream>>>(yin, A, of_g1, of_b1, 1);
        conv3x3_kernel<1><<<4096, 256, 0, stream>>>(A, YT, of_w1, of_cb1, tv);
        gn_kernel<<<8192, 256, 0, stream>>>(YT, A, of_g2, of_b2, 1);
        conv3x3_kernel<1><<<4096, 256, 0, stream>>>(A, YT, of_w2, of_cb2, tv);
        gn_kernel<<<8192, 256, 0, stream>>>(YT, K, of_g3, of_b3, 0);
    };

    for (int s = 0; s < 8; ++s) {
        const float t0 = h * (float)s;
        odefunc(y, t0);                                    // k1
        rk_update_kernel<<<4096, 256, 0, stream>>>(y, K, ACC, YT,
                                                   h / 6.f, 0.5f * h, 0, n4);
        odefunc(YT, t0 + 0.5f * h);                        // k2
        rk_update_kernel<<<4096, 256, 0, stream>>>(y, K, ACC, YT,
                                                   h / 3.f, 0.5f * h, 1, n4);
        odefunc(YT, t0 + 0.5f * h);                        // k3
        rk_update_kernel<<<4096, 256, 0, stream>>>(y, K, ACC, YT,
                                                   h / 3.f, h, 1, n4);
        odefunc(YT, t0 + h);                               // k4
        rk_update_kernel<<<4096, 256, 0, stream>>>(y, K, ACC, YT,
                                                   h / 6.f, 0.f, 2, n4);
    }
}